// Round 2
// baseline (346.789 us; speedup 1.0000x reference)
//
#include <hip/hip_runtime.h>
#include <stdint.h>

// MHA: B=2, S=2048, D=1024, H=16, Dh=64.  All GEMMs are 4096x1024x1024.
// Strategy: convert to bf16, MFMA everything (fp32 accum), flash attention.

typedef unsigned short u16;
typedef __attribute__((ext_vector_type(8))) short bf16x8;   // 8 bf16 = 4 VGPR
typedef __attribute__((ext_vector_type(4))) float f32x4;

#define MFMA16 __builtin_amdgcn_mfma_f32_16x16x32_bf16

#define GM 4096
#define GN 1024
#define GK 1024
#define S_LEN 2048
#define NH 16
#define DH 64

__device__ __forceinline__ u16 f2bf(float f) {
    union { float f; uint32_t u; } v; v.f = f;
    return (u16)((v.u + 0x7fffu + ((v.u >> 16) & 1u)) >> 16);
}

// ---------------- fp32 -> bf16 bulk convert (8 elems/thread) ----------------
__global__ __launch_bounds__(256) void cvt_bf16_kernel(const float* __restrict__ src,
                                                       u16* __restrict__ dst, int n8) {
    int i = blockIdx.x * 256 + threadIdx.x;
    if (i >= n8) return;
    const f32x4* s = (const f32x4*)src + (size_t)i * 2;
    f32x4 a = s[0], b = s[1];
    union { bf16x8 v; u16 u[8]; } o;
    o.u[0] = f2bf(a[0]); o.u[1] = f2bf(a[1]); o.u[2] = f2bf(a[2]); o.u[3] = f2bf(a[3]);
    o.u[4] = f2bf(b[0]); o.u[5] = f2bf(b[1]); o.u[6] = f2bf(b[2]); o.u[7] = f2bf(b[3]);
    *(bf16x8*)(dst + (size_t)i * 8) = o.v;
}

// ---------------- 128x128-tile bf16 GEMM core: C = A @ W^T + bias ----------------
// A: [4096,1024] bf16 row-major; W: [1024,1024] bf16 row-major (i.e. B^T input).
// mode 0: C bf16 -> [B,H,S,Dh];  mode 1: C bf16 -> [B,H,Dh,S];  mode 2: C fp32 row-major.
__device__ __forceinline__ void gemm_core(const u16* __restrict__ A,
                                          const u16* __restrict__ W,
                                          const float* __restrict__ bias,
                                          void* __restrict__ Cout, int mode,
                                          u16* As, u16* Bs) {
    const int t  = threadIdx.x;
    const int l  = t & 63;
    const int w  = t >> 6;
    const int wr = w >> 1, wc = w & 1;           // 2x2 wave grid, 64x64 per wave
    const int cl = l & 15, g = l >> 4;
    const int mbase = blockIdx.y * 128;
    const int nbase = blockIdx.x * 128;

    f32x4 acc[4][4];
    f32x4 zero = {0.f, 0.f, 0.f, 0.f};
    #pragma unroll
    for (int i = 0; i < 4; ++i)
        #pragma unroll
        for (int j = 0; j < 4; ++j) acc[i][j] = zero;

    for (int kt = 0; kt < GK; kt += 64) {
        // stage A tile [128][64] and W tile [128][64] into LDS (linear, lane-ordered)
        #pragma unroll
        for (int r = 0; r < 4; ++r) {
            int chunk = r * 256 + t;             // wave-uniform base + lane*16B
            int row = chunk >> 3;
            int col = (chunk & 7) << 3;
            __builtin_amdgcn_global_load_lds(
                (const __attribute__((address_space(1))) void*)(A + (size_t)(mbase + row) * GK + kt + col),
                (__attribute__((address_space(3))) void*)(As + chunk * 8), 16, 0, 0);
        }
        #pragma unroll
        for (int r = 0; r < 4; ++r) {
            int chunk = r * 256 + t;
            int row = chunk >> 3;
            int col = (chunk & 7) << 3;
            __builtin_amdgcn_global_load_lds(
                (const __attribute__((address_space(1))) void*)(W + (size_t)(nbase + row) * GK + kt + col),
                (__attribute__((address_space(3))) void*)(Bs + chunk * 8), 16, 0, 0);
        }
        __syncthreads();
        #pragma unroll
        for (int ks = 0; ks < 2; ++ks) {
            bf16x8 af[4], bfr[4];
            #pragma unroll
            for (int mi = 0; mi < 4; ++mi)
                af[mi] = *(const bf16x8*)&As[(wr * 64 + mi * 16 + cl) * 64 + ks * 32 + g * 8];
            #pragma unroll
            for (int nj = 0; nj < 4; ++nj)
                bfr[nj] = *(const bf16x8*)&Bs[(wc * 64 + nj * 16 + cl) * 64 + ks * 32 + g * 8];
            #pragma unroll
            for (int mi = 0; mi < 4; ++mi)
                #pragma unroll
                for (int nj = 0; nj < 4; ++nj)
                    acc[mi][nj] = MFMA16(af[mi], bfr[nj], acc[mi][nj], 0, 0, 0);
        }
        __syncthreads();
    }

    // epilogue: C/D layout col = lane&15, row = (lane>>4)*4 + reg (m89-verified)
    #pragma unroll
    for (int mi = 0; mi < 4; ++mi) {
        #pragma unroll
        for (int nj = 0; nj < 4; ++nj) {
            int n = nbase + wc * 64 + nj * 16 + cl;
            float bv = bias[n];
            #pragma unroll
            for (int r = 0; r < 4; ++r) {
                int m = mbase + wr * 64 + mi * 16 + g * 4 + r;
                float vv = acc[mi][nj][r] + bv;
                if (mode == 2) {
                    ((float*)Cout)[(size_t)m * GN + n] = vv;
                } else {
                    int b = m >> 11, s = m & 2047;
                    int h = n >> 6, dh = n & 63;
                    if (mode == 0)       // [B,H,S,Dh]
                        ((u16*)Cout)[(((size_t)(b * NH + h)) * S_LEN + s) * DH + dh] = f2bf(vv);
                    else                 // [B,H,Dh,S]  (V transposed)
                        ((u16*)Cout)[(((size_t)(b * NH + h)) * DH + dh) * S_LEN + s] = f2bf(vv);
                }
            }
        }
    }
}

// projections: Q,K,V in one launch (blockIdx.z selects), 768 blocks = 3/CU
__global__ __launch_bounds__(256) void proj_gemm(
        const u16* __restrict__ qbf, const u16* __restrict__ kbf, const u16* __restrict__ vbf,
        const u16* __restrict__ Wqb, const u16* __restrict__ Wkb, const u16* __restrict__ Wvb,
        const float* __restrict__ bq, const float* __restrict__ bk, const float* __restrict__ bv,
        u16* __restrict__ Qb, u16* __restrict__ Kb, u16* __restrict__ Vtb) {
    __shared__ u16 As[128 * 64];
    __shared__ u16 Bs[128 * 64];
    int z = blockIdx.z;
    const u16* A   = (z == 0) ? qbf : (z == 1) ? kbf : vbf;
    const u16* W   = (z == 0) ? Wqb : (z == 1) ? Wkb : Wvb;
    const float* b = (z == 0) ? bq  : (z == 1) ? bk  : bv;
    u16* C         = (z == 0) ? Qb  : (z == 1) ? Kb  : Vtb;
    gemm_core(A, W, b, (void*)C, (z == 2) ? 1 : 0, As, Bs);
}

__global__ __launch_bounds__(256) void out_gemm(const u16* __restrict__ A,
                                                const u16* __restrict__ W,
                                                const float* __restrict__ bias,
                                                float* __restrict__ C) {
    __shared__ u16 As[128 * 64];
    __shared__ u16 Bs[128 * 64];
    gemm_core(A, W, bias, (void*)C, 2, As, Bs);
}

// ---------------- flash attention ----------------
// Q,K: [B*H, S, 64] bf16; Vt: [B*H, 64, S] bf16; O: [B, S, 1024] bf16.
// 4 waves/block, 16 q-rows/wave, KV block = 32, online softmax.
__global__ __launch_bounds__(256) void attn_kernel(const u16* __restrict__ Q,
                                                   const u16* __restrict__ Kb,
                                                   const u16* __restrict__ Vt,
                                                   u16* __restrict__ O) {
    __shared__ u16 Plds[4][16 * 40];             // per-wave P scratch, padded stride 40
    const int t = threadIdx.x, l = t & 63, w = t >> 6;
    const int cl = l & 15, g = l >> 4;
    const int bh = blockIdx.x;                   // 0..31
    const int b = bh >> 4, h = bh & 15;
    const int qw = blockIdx.y * 64 + w * 16;     // this wave's q-row base

    const u16* Qp = Q  + ((size_t)bh * S_LEN + qw) * DH;
    const u16* Kp = Kb + (size_t)bh * S_LEN * DH;
    const u16* Vp = Vt + (size_t)bh * DH * S_LEN;

    // Q A-fragments (row = lane&15 = q-local, k = (lane>>4)*8+e), held for whole loop
    bf16x8 qf0 = *(const bf16x8*)(Qp + (size_t)cl * DH + g * 8);
    bf16x8 qf1 = *(const bf16x8*)(Qp + (size_t)cl * DH + 32 + g * 8);

    float m_r[4], l_r[4];
    f32x4 oacc[4];
    f32x4 zero = {0.f, 0.f, 0.f, 0.f};
    #pragma unroll
    for (int r = 0; r < 4; ++r) { m_r[r] = -1e30f; l_r[r] = 0.f; }
    #pragma unroll
    for (int tt = 0; tt < 4; ++tt) oacc[tt] = zero;

    u16* P = Plds[w];

    for (int kv = 0; kv < S_LEN; kv += 32) {
        // K B-fragments: col = lane&15 = kv-local, k = d
        const u16* K0 = Kp + (size_t)(kv + cl) * DH + g * 8;
        const u16* K1 = Kp + (size_t)(kv + 16 + cl) * DH + g * 8;
        bf16x8 kf00 = *(const bf16x8*)(K0);
        bf16x8 kf01 = *(const bf16x8*)(K0 + 32);
        bf16x8 kf10 = *(const bf16x8*)(K1);
        bf16x8 kf11 = *(const bf16x8*)(K1 + 32);

        f32x4 s0 = zero, s1 = zero;              // S[q][kv]: row=q=(g*4+r), col=kv=cl
        s0 = MFMA16(qf0, kf00, s0, 0, 0, 0);
        s0 = MFMA16(qf1, kf01, s0, 0, 0, 0);
        s1 = MFMA16(qf0, kf10, s1, 0, 0, 0);
        s1 = MFMA16(qf1, kf11, s1, 0, 0, 0);

        float v0[4], v1[4], mx[4];
        #pragma unroll
        for (int r = 0; r < 4; ++r) {
            v0[r] = s0[r] * 0.125f;              // 1/sqrt(64)
            v1[r] = s1[r] * 0.125f;
            mx[r] = fmaxf(v0[r], v1[r]);
        }
        #pragma unroll
        for (int d = 1; d < 16; d <<= 1)
            #pragma unroll
            for (int r = 0; r < 4; ++r)
                mx[r] = fmaxf(mx[r], __shfl_xor(mx[r], d, 64));

        float p0[4], p1[4], rs[4];
        #pragma unroll
        for (int r = 0; r < 4; ++r) {
            float mn = fmaxf(m_r[r], mx[r]);
            float c  = __expf(m_r[r] - mn);
            m_r[r] = mn;
            p0[r] = __expf(v0[r] - mn);
            p1[r] = __expf(v1[r] - mn);
            rs[r] = p0[r] + p1[r];
            l_r[r] *= c;
            #pragma unroll
            for (int tt = 0; tt < 4; ++tt) oacc[tt][r] = oacc[tt][r] * c;
        }
        #pragma unroll
        for (int d = 1; d < 16; d <<= 1)
            #pragma unroll
            for (int r = 0; r < 4; ++r)
                rs[r] += __shfl_xor(rs[r], d, 64);
        #pragma unroll
        for (int r = 0; r < 4; ++r) l_r[r] += rs[r];

        // transpose P through LDS into A-fragment layout (wave-private, no barrier)
        #pragma unroll
        for (int r = 0; r < 4; ++r) {
            P[(g * 4 + r) * 40 + cl]      = f2bf(p0[r]);
            P[(g * 4 + r) * 40 + 16 + cl] = f2bf(p1[r]);
        }
        bf16x8 pf = *(const bf16x8*)&P[cl * 40 + g * 8];

        #pragma unroll
        for (int tt = 0; tt < 4; ++tt) {
            // V B-fragment: col = dh-local = cl, k = kv-local -> contiguous in Vt
            bf16x8 vf = *(const bf16x8*)(Vp + (size_t)(tt * 16 + cl) * S_LEN + kv + g * 8);
            oacc[tt] = MFMA16(pf, vf, oacc[tt], 0, 0, 0);
        }
    }

    #pragma unroll
    for (int tt = 0; tt < 4; ++tt) {
        #pragma unroll
        for (int r = 0; r < 4; ++r) {
            int q = qw + g * 4 + r;
            float val = oacc[tt][r] / l_r[r];
            O[((size_t)b * S_LEN + q) * GN + h * DH + tt * 16 + cl] = f2bf(val);
        }
    }
}

// ---------------- launch ----------------
extern "C" void kernel_launch(void* const* d_in, const int* in_sizes, int n_in,
                              void* d_out, int out_size, void* d_ws, size_t ws_size,
                              hipStream_t stream) {
    const float* query = (const float*)d_in[0];
    const float* key   = (const float*)d_in[1];
    const float* value = (const float*)d_in[2];
    const float* Wq = (const float*)d_in[3];
    const float* bq = (const float*)d_in[4];
    const float* Wk = (const float*)d_in[5];
    const float* bk = (const float*)d_in[6];
    const float* Wv = (const float*)d_in[7];
    const float* bv = (const float*)d_in[8];
    const float* Wo = (const float*)d_in[9];
    const float* bo = (const float*)d_in[10];
    float* out = (float*)d_out;

    // workspace layout (bf16 elements), total 64 MB
    u16* ws = (u16*)d_ws;
    const size_t MD = (size_t)GM * GN;   // 4,194,304
    const size_t WW = (size_t)GN * GK;   // 1,048,576
    u16* qbf = ws;
    u16* kbf = qbf + MD;
    u16* vbf = kbf + MD;
    u16* Wqb = vbf + MD;
    u16* Wkb = Wqb + WW;
    u16* Wvb = Wkb + WW;
    u16* Wob = Wvb + WW;
    u16* Qb  = Wob + WW;
    u16* Kbf = Qb  + MD;
    u16* Vtb = Kbf + MD;
    u16* Ob  = Vtb + MD;

    // 1) convert inputs + weights to bf16
    cvt_bf16_kernel<<<(int)(MD / 8 / 256), 256, 0, stream>>>(query, qbf, (int)(MD / 8));
    cvt_bf16_kernel<<<(int)(MD / 8 / 256), 256, 0, stream>>>(key,   kbf, (int)(MD / 8));
    cvt_bf16_kernel<<<(int)(MD / 8 / 256), 256, 0, stream>>>(value, vbf, (int)(MD / 8));
    cvt_bf16_kernel<<<(int)(WW / 8 / 256), 256, 0, stream>>>(Wq, Wqb, (int)(WW / 8));
    cvt_bf16_kernel<<<(int)(WW / 8 / 256), 256, 0, stream>>>(Wk, Wkb, (int)(WW / 8));
    cvt_bf16_kernel<<<(int)(WW / 8 / 256), 256, 0, stream>>>(Wv, Wvb, (int)(WW / 8));
    cvt_bf16_kernel<<<(int)(WW / 8 / 256), 256, 0, stream>>>(Wo, Wob, (int)(WW / 8));

    // 2) Q/K/V projections (one launch, z selects)
    dim3 gproj(GN / 128, GM / 128, 3);
    proj_gemm<<<gproj, 256, 0, stream>>>(qbf, kbf, vbf, Wqb, Wkb, Wvb,
                                         bq, bk, bv, Qb, Kbf, Vtb);

    // 3) flash attention
    dim3 gattn(2 * NH, S_LEN / 64);
    attn_kernel<<<gattn, 256, 0, stream>>>(Qb, Kbf, Vtb, Ob);

    // 4) output projection -> fp32 d_out
    dim3 gout(GN / 128, GM / 128);
    out_gemm<<<gout, 256, 0, stream>>>(Ob, Wob, bo, out);
}